// Round 17
// baseline (205.790 us; speedup 1.0000x reference)
//
#include <hip/hip_runtime.h>
#include <math.h>

// Problem constants (fixed by reference): B=64, N=512, D=64, H=4, C=64, L=3
// Workspace layout (floats), ws >= 256 MB:
//   xbuf [0 .. 2097152)          : layer activations x (8 MB)
//   hT   [2097152 .. 10485760)   : h channel-pair interleaved (R32) (32 MB)
//   meta [10485760 .. 11534336)  : g_rE float4 + g_abk float4 (4 MB)
//   pooled [11534336 .. 11538432): per-(b,c) over-n sums (16 KB)
//   g_sd  [11538432 .. +262144)  : packed (s,d) dots float2[256*512] (1 MB)
// History: R23 237 -> R27 236 -> R28 232 -> R29 229 -> R30 201 -> R31 197.5
// -> R32 196.1 BEST. Message-reduction mechanism 5-for-5; XCD grouping 2x.
// R33 (this): UN-fuse lin from prep. The fusion pinned lin to 1 block/CU
// (2 waves/SIMD) though lin's work floor is ~6us; only prep needs the
// block-wide s/d. New lin_kernel: grid 1024 = (b,head,q4), XCD swizzle
// id%8==b%8 (x[b]/hT[b] stay on agg's XCD), wave owns 2 tiles, W-frags in
// registers, R32 tile body + channel-pair hT store VERBATIM; s/d exits via
// packed float2 g_sd. prep_kernel: R29 body verbatim at 256thr (no guards),
// staged from g_sd. agg/readout untouched. All fp32 op order preserved ->
// absmax must stay 1.907349e-06.
// Decision rule: >=196.1 -> revert to exact R32, declare ~196 the floor.

using short8  = __attribute__((ext_vector_type(8))) short;
using floatx4 = __attribute__((ext_vector_type(4))) float;

__device__ inline unsigned short f2bf(float f) {
    union { float f; unsigned u; } v; v.f = f;
    unsigned u = v.u + 0x7FFFu + ((v.u >> 16) & 1u);   // round-to-nearest-even
    return (unsigned short)(u >> 16);
}
__device__ inline float bf2f(unsigned short s) {
    union { float f; unsigned u; } v; v.u = ((unsigned)s) << 16;
    return v.f;
}

// 8 floats (two float4) -> split-bf16 hi/lo short8 fragments, in registers.
__device__ inline void cvt8(const float4 a, const float4 b, short8& hi, short8& lo) {
    float f[8] = {a.x, a.y, a.z, a.w, b.x, b.y, b.z, b.w};
    short8 H, L;
#pragma unroll
    for (int i = 0; i < 8; ++i) {
        unsigned short h = f2bf(f[i]);
        H[i] = (short)h;
        L[i] = (short)f2bf(f[i] - bf2f(h));
    }
    hi = H; lo = L;
}

// ---------------------------------------------------------------------------
// Kernel A: lin v6 (R33) — grid 1024 = (b, head, q4), 256 thr (4 waves),
// 4 blocks/CU. Wave wv owns tiles q4*8+wv and q4*8+wv+4 (1-deep prefetch).
// XCD swizzle id%8==b%8. R32 channel-pair hT store. s/d -> packed g_sd.
// ---------------------------------------------------------------------------
__global__ __launch_bounds__(256) void lin_kernel(const float* __restrict__ x,
                                                  const float* __restrict__ W,
                                                  const float* __restrict__ att_src,
                                                  const float* __restrict__ att_dst,
                                                  float* __restrict__ hT,
                                                  float2* __restrict__ g_sd) {
    __shared__ unsigned short WH[64 * 72], WL[64 * 72];

    const int t  = threadIdx.x;
    // Decode (b, head, q4) with id%8 == b%8.
    const int r8   = blockIdx.x & 7;
    const int rest = blockIdx.x >> 3;      // 0..127
    const int bhi  = rest >> 4;            // 0..7
    const int ct   = (rest >> 2) & 3;      // head
    const int q4   = rest & 3;             // tile quarter
    const int b    = (bhi << 3) | r8;      // 0..63
    const int bh   = b * 4 + ct;
    const int c0   = ct * 64;

    // ---- W staging + convert, ONCE per block (R23 layout) ----
#pragma unroll
    for (int qq = 0; qq < 4; ++qq) {
        int f = qq * 256 + t;
        int wrow = f >> 4, d4 = f & 15;
        float4 v = *(const float4*)(W + (size_t)(c0 + wrow) * 64 + d4 * 4);
        unsigned short h0 = f2bf(v.x), h1 = f2bf(v.y), h2 = f2bf(v.z), h3 = f2bf(v.w);
        ushort4 hi = make_ushort4(h0, h1, h2, h3);
        ushort4 lo = make_ushort4(f2bf(v.x - bf2f(h0)), f2bf(v.y - bf2f(h1)),
                                  f2bf(v.z - bf2f(h2)), f2bf(v.w - bf2f(h3)));
        *(ushort4*)&WH[wrow * 72 + d4 * 4] = hi;
        *(ushort4*)&WL[wrow * 72 + d4 * 4] = lo;
    }
    __syncthreads();

    const int lane = t & 63, wv = t >> 6;   // wv = 0..3
    const int mrow = lane & 15, quad = lane >> 4;

    // ---- per-wave W fragments for ALL 4 channel groups (REGISTERS) ----
    short8 bhf[4][2], blf[4][2];
#pragma unroll
    for (int g = 0; g < 4; ++g)
#pragma unroll
        for (int kk = 0; kk < 2; ++kk) {
            int ko = kk * 32 + quad * 8;
            bhf[g][kk] = *(const short8*)&WH[(g * 16 + mrow) * 72 + ko];
            blf[g][kk] = *(const short8*)&WL[(g * 16 + mrow) * 72 + ko];
        }
    float as_g[4], ad_g[4];
#pragma unroll
    for (int g = 0; g < 4; ++g) {
        as_g[g] = att_src[c0 + g * 16 + mrow];
        ad_g[g] = att_dst[c0 + g * 16 + mrow];
    }

    // ---- wave wv: tiles tl0 and tl0+4 (1-deep prefetch) ----
    const int tl0 = q4 * 8 + wv;
    const float* xbase = x + (size_t)(b * 512 + mrow) * 64 + quad * 8;
    float4 nxa = *(const float4*)(xbase + (size_t)tl0 * 1024);
    float4 nxb = *(const float4*)(xbase + (size_t)tl0 * 1024 + 4);
    float4 nxc = *(const float4*)(xbase + (size_t)tl0 * 1024 + 32);
    float4 nxd = *(const float4*)(xbase + (size_t)tl0 * 1024 + 36);

#pragma unroll 1
    for (int ii = 0; ii < 2; ++ii) {
        const int tl = tl0 + ii * 4;
        float4 xa = nxa, xb = nxb, xc = nxc, xd = nxd;
        if (ii == 0) {
            const float* nb = xbase + (size_t)(tl + 4) * 1024;
            nxa = *(const float4*)(nb);
            nxb = *(const float4*)(nb + 4);
            nxc = *(const float4*)(nb + 32);
            nxd = *(const float4*)(nb + 36);
        }
        short8 ah0, al0, ah1, al1;
        cvt8(xa, xb, ah0, al0);
        cvt8(xc, xd, ah1, al1);

        floatx4 acc[4];
#pragma unroll
        for (int g = 0; g < 4; ++g) {
            floatx4 a = {0.f, 0.f, 0.f, 0.f};
            a = __builtin_amdgcn_mfma_f32_16x16x32_bf16(ah0, bhf[g][0], a, 0, 0, 0);
            a = __builtin_amdgcn_mfma_f32_16x16x32_bf16(ah1, bhf[g][1], a, 0, 0, 0);
            a = __builtin_amdgcn_mfma_f32_16x16x32_bf16(ah0, blf[g][0], a, 0, 0, 0);
            a = __builtin_amdgcn_mfma_f32_16x16x32_bf16(ah1, blf[g][1], a, 0, 0, 0);
            a = __builtin_amdgcn_mfma_f32_16x16x32_bf16(al0, bhf[g][0], a, 0, 0, 0);
            a = __builtin_amdgcn_mfma_f32_16x16x32_bf16(al1, bhf[g][1], a, 0, 0, 0);
            acc[g] = a;
        }

        // ---- R32 channel-pair interleaved hT store via lane-pair exchange.
        const int nbase = b * 512 + tl * 16 + quad * 4;
#pragma unroll
        for (int g = 0; g < 4; ++g) {
            float tmp0 = __shfl_xor(acc[g][0], 1, 64);
            float tmp1 = __shfl_xor(acc[g][1], 1, 64);
            float tmp2 = __shfl_xor(acc[g][2], 1, 64);
            float tmp3 = __shfl_xor(acc[g][3], 1, 64);
            const size_t cp = (size_t)(ct * 32 + g * 8 + (mrow >> 1));
            if ((mrow & 1) == 0) {
                *(float4*)&hT[cp * 65536 + (size_t)nbase * 2] =
                    make_float4(acc[g][0], tmp0, acc[g][1], tmp1);
            } else {
                *(float4*)&hT[cp * 65536 + (size_t)(nbase + 2) * 2] =
                    make_float4(tmp2, acc[g][2], tmp3, acc[g][3]);
            }
        }

        float ps[4], pd[4];
#pragma unroll
        for (int reg = 0; reg < 4; ++reg) {
            ps[reg] = acc[0][reg] * as_g[0] + acc[1][reg] * as_g[1]
                    + acc[2][reg] * as_g[2] + acc[3][reg] * as_g[3];
            pd[reg] = acc[0][reg] * ad_g[0] + acc[1][reg] * ad_g[1]
                    + acc[2][reg] * ad_g[2] + acc[3][reg] * ad_g[3];
        }
#pragma unroll
        for (int m = 1; m <= 8; m <<= 1) {
#pragma unroll
            for (int reg = 0; reg < 4; ++reg) {
                ps[reg] += __shfl_xor(ps[reg], m, 64);
                pd[reg] += __shfl_xor(pd[reg], m, 64);
            }
        }
        if (mrow < 4) {
            g_sd[bh * 512 + tl * 16 + quad * 4 + mrow] =
                make_float2(ps[mrow], pd[mrow]);
        }
    }
}

// ---------------------------------------------------------------------------
// Kernel B1: prep v6 (R33) — R29 prep body verbatim at 256 threads,
// staged from packed g_sd. grid 256 = bh.
// ---------------------------------------------------------------------------
__global__ __launch_bounds__(256) void prep_kernel(const float2* __restrict__ g_sd,
                                                   float4* __restrict__ g_rE,
                                                   float4* __restrict__ g_abk) {
    __shared__ float sA[512], dA[512];
    __shared__ int   s_idxE[512];
    __shared__ float z1suf[513], z2pre[513];
    __shared__ float wred[8];

    const int bh = blockIdx.x;
    const int t = threadIdx.x;
    const int lane = t & 63;
    const int wid = t >> 6;

    for (int rr = 0; rr < 2; ++rr) {
        int j = t + rr * 256;
        float2 sd = g_sd[bh * 512 + j];
        sA[j] = sd.x;
        dA[j] = sd.y;
    }
    __syncthreads();

    float dreg[2] = {dA[t], dA[t + 256]};

    float v0 = sA[2 * t], v1 = sA[2 * t + 1];
    int id0 = 2 * t, id1 = 2 * t + 1;
    for (int k = 2; k <= 512; k <<= 1) {
        for (int j = k >> 1; j >= 1; j >>= 1) {
            bool asc = ((t & (k >> 1)) == 0);
            if (j == 1) {
                bool sw = asc ? (v0 > v1) : (v0 < v1);
                if (sw) { float tv = v0; v0 = v1; v1 = tv; int ti = id0; id0 = id1; id1 = ti; }
            } else if (j <= 64) {
                int m = j >> 1;
                float w0 = __shfl_xor(v0, m, 64);
                int  wi0 = __shfl_xor(id0, m, 64);
                float w1 = __shfl_xor(v1, m, 64);
                int  wi1 = __shfl_xor(id1, m, 64);
                bool low = ((t & m) == 0);
                bool wantmin = (low == asc);
                if (wantmin ? (w0 < v0) : (w0 > v0)) { v0 = w0; id0 = wi0; }
                if (wantmin ? (w1 < v1) : (w1 > v1)) { v1 = w1; id1 = wi1; }
            } else {
                int m = j >> 1;
                sA[2 * t] = v0; sA[2 * t + 1] = v1;
                s_idxE[2 * t] = id0; s_idxE[2 * t + 1] = id1;
                __syncthreads();
                int tp = t ^ m;
                float w0 = sA[2 * tp], w1 = sA[2 * tp + 1];
                int wi0 = s_idxE[2 * tp], wi1 = s_idxE[2 * tp + 1];
                bool low = ((t & m) == 0);
                bool wantmin = (low == asc);
                if (wantmin ? (w0 < v0) : (w0 > v0)) { v0 = w0; id0 = wi0; }
                if (wantmin ? (w1 < v1) : (w1 > v1)) { v1 = w1; id1 = wi1; }
                __syncthreads();
            }
        }
    }

    sA[2 * t] = v0; sA[2 * t + 1] = v1;
    __syncthreads();
    const float M = sA[511];
    float e1_0 = __expf(v0 - M), e1_1 = __expf(v1 - M);
    float e2_0 = __expf(0.2f * (v0 - M)), e2_1 = __expf(0.2f * (v1 - M));
    {
        const int base = bh * 512;
        g_rE[base + id0] = make_float4(__int_as_float(2 * t),     e1_0, e2_0, 0.f);
        g_rE[base + id1] = make_float4(__int_as_float(2 * t + 1), e1_1, e2_1, 0.f);
    }

    float S1 = e1_0 + e1_1, S2 = e2_0 + e2_1;
    float i1 = S1, i2 = S2;
    for (int off = 1; off < 64; off <<= 1) {
        float u1 = __shfl_up(i1, off, 64);
        float u2 = __shfl_up(i2, off, 64);
        if (lane >= off) { i1 += u1; i2 += u2; }
    }
    if (lane == 63) { wred[wid] = i1; wred[4 + wid] = i2; }
    __syncthreads();
    float off1 = 0.f, off2 = 0.f;
    for (int w = 0; w < wid; ++w) { off1 += wred[w]; off2 += wred[4 + w]; }
    const float T1 = wred[0] + wred[1] + wred[2] + wred[3];
    const float T2 = wred[4] + wred[5] + wred[6] + wred[7];
    float pre1 = off1 + i1 - S1;
    float pre2 = off2 + i2 - S2;
    z1suf[2 * t] = T1 - pre1;
    z1suf[2 * t + 1] = T1 - pre1 - e1_0;
    z2pre[2 * t] = pre2;
    z2pre[2 * t + 1] = pre2 + e2_0;
    if (t == 0) { z1suf[512] = 0.f; z2pre[512] = T2; }
    __syncthreads();

    for (int rr = 0; rr < 2; ++rr) {
        int i = t + rr * 256;
        float d = dreg[rr];
        int lo = 0, hi = 512;
        while (lo < hi) {
            int mid = (lo + hi) >> 1;
            if (d + sA[mid] >= 0.f) hi = mid; else lo = mid + 1;
        }
        int k = lo;
        float g = d + M;
        float G = (g >= 0.f) ? g : 0.2f * g;
        float al = __expf(g - G);
        float be = __expf(0.2f * g - G);
        float Z = al * z1suf[k] + be * z2pre[k];
        float inv = 1.0f / Z;
        g_abk[bh * 512 + i] = make_float4(al * inv, be * inv,
                                          __int_as_float(k), 0.f);
    }
}

// ---------------------------------------------------------------------------
// Kernel B2: attn_agg_fin v11 (R32, UNCHANGED) — float4 LDS tables + float2
// hT reads + fused pooling + optional x store. grid 2048, 256 thr.
// ---------------------------------------------------------------------------
__global__ __launch_bounds__(256) void attn_agg_fin(const float* __restrict__ hT,
                                                    const float4* __restrict__ g_rE,
                                                    const float4* __restrict__ g_abk,
                                                    const float* __restrict__ bias,
                                                    float* __restrict__ x,
                                                    float* __restrict__ pooled,
                                                    int storex) {
    // R27 bijective swizzle: id%8 = b%8.
    const int r8 = blockIdx.x & 7;
    const int qq = blockIdx.x >> 3;
    const int cg = qq & 31;                // 0..31
    const int b  = ((qq >> 5) << 3) | r8;  // 0..63
    const int c0 = cg * 2;
    const int t = threadIdx.x;
    const int lane = t & 63, wv = t >> 6;  // wv = head 0..3

    __shared__ float4 A12[4][512];         // {A1c0, A2c0, A1c1, A2c1}
    __shared__ float tots[4][2];
    __shared__ float sredP[4][2];

    {
        const int bh = b * 4 + wv;
        const int base = bh * 512;
        const float* hTb = hT + (size_t)(wv * 32 + cg) * 65536 + (size_t)(b * 512) * 2;
#pragma unroll
        for (int it = 0; it < 8; ++it) {
            int j = it * 64 + lane;
            float4 rE = g_rE[base + j];          // packed (rank, E1, E2)
            int rk = __float_as_int(rE.x);
            float2 hv = *(const float2*)&hTb[j * 2];
            int pk = ((rk & 7) << 6) | (rk >> 3);
            A12[wv][pk] = make_float4(rE.y * hv.x, rE.z * hv.x,
                                      rE.y * hv.y, rE.z * hv.y);   // one b128
        }
        float a1c0[8], a2c0[8], a1c1[8], a2c1[8];
#pragma unroll
        for (int i = 0; i < 8; ++i) {
            float4 vv = A12[wv][i * 64 + lane];
            a1c0[i] = vv.x; a2c0[i] = vv.y; a1c1[i] = vv.z; a2c1[i] = vv.w;
        }
        float s10 = 0.f, s20 = 0.f, s11 = 0.f, s21 = 0.f;
#pragma unroll
        for (int i = 0; i < 8; ++i) {
            s10 += a1c0[i]; s20 += a2c0[i]; s11 += a1c1[i]; s21 += a2c1[i];
        }
        float suf0 = s10, suf1 = s11;
#pragma unroll
        for (int off = 1; off < 64; off <<= 1) {
            float u0 = __shfl_down(suf0, off, 64);
            float u1 = __shfl_down(suf1, off, 64);
            if (lane + off < 64) { suf0 += u0; suf1 += u1; }
        }
        float run0 = suf0 - s10, run1 = suf1 - s11;      // exclusive suffix
        float pre0 = s20, pre1 = s21;
#pragma unroll
        for (int off = 1; off < 64; off <<= 1) {
            float u0 = __shfl_up(pre0, off, 64);
            float u1 = __shfl_up(pre1, off, 64);
            if (lane >= off) { pre0 += u0; pre1 += u1; }
        }
        float run20 = pre0 - s20, run21 = pre1 - s21;    // exclusive prefix
        if (lane == 63) { tots[wv][0] = pre0; tots[wv][1] = pre1; }
#pragma unroll
        for (int i = 7; i >= 0; --i) {
            run0 += a1c0[i]; a1c0[i] = run0;             // incl suffix
            run1 += a1c1[i]; a1c1[i] = run1;
        }
#pragma unroll
        for (int i = 0; i < 8; ++i) {
            float tv0 = a2c0[i]; a2c0[i] = run20; run20 += tv0;  // excl prefix
            float tv1 = a2c1[i]; a2c1[i] = run21; run21 += tv1;
        }
#pragma unroll
        for (int i = 0; i < 8; ++i)
            A12[wv][i * 64 + lane] = make_float4(a1c0[i], a2c0[i],
                                                 a1c1[i], a2c1[i]);  // one b128
    }
    __syncthreads();

    const float bv0 = bias[c0], bv1 = bias[c0 + 1];
    float p0 = 0.f, p1 = 0.f;              // per-thread pooled partials
#pragma unroll
    for (int rr = 0; rr < 2; ++rr) {
        const int i = t + rr * 256;
        float a0 = 0.f, a1 = 0.f;
#pragma unroll
        for (int head = 0; head < 4; ++head) {
            const int base = (b * 4 + head) * 512;
            float4 abk = g_abk[base + i];        // packed (aZ, bZ, k)
            int k = __float_as_int(abk.z);
            if (k < 512) {
                int pk = ((k & 7) << 6) | (k >> 3);
                float4 vv = A12[head][pk];       // one random b128
                a0 += abk.x * vv.x + abk.y * vv.y;
                a1 += abk.x * vv.z + abk.y * vv.w;
            } else {
                a0 += abk.y * tots[head][0];
                a1 += abk.y * tots[head][1];
            }
        }
        float2 o = make_float2(fmaxf(0.25f * a0 + bv0, 0.f),
                               fmaxf(0.25f * a1 + bv1, 0.f));
        if (storex) *(float2*)&x[(size_t)(b * 512 + i) * 64 + c0] = o;
        p0 += o.x; p1 += o.y;
    }

    // Fused pooling: this block exclusively owns (b, c0..c0+1) over all n.
#pragma unroll
    for (int m = 1; m <= 32; m <<= 1) {
        p0 += __shfl_xor(p0, m, 64);
        p1 += __shfl_xor(p1, m, 64);
    }
    if (lane == 0) { sredP[wv][0] = p0; sredP[wv][1] = p1; }
    __syncthreads();
    if (t == 0) {
        pooled[b * 64 + c0]     = sredP[0][0] + sredP[1][0] + sredP[2][0] + sredP[3][0];
        pooled[b * 64 + c0 + 1] = sredP[0][1] + sredP[1][1] + sredP[2][1] + sredP[3][1];
    }
}

// ---------------------------------------------------------------------------
// Kernel D: readout v2 — consumes 16KB pooled sums. grid 64 x 64 threads.
// ---------------------------------------------------------------------------
__global__ __launch_bounds__(64) void readout_kernel(const float* __restrict__ pooled,
                                                     const float* __restrict__ rw,
                                                     const float* __restrict__ rb,
                                                     float* __restrict__ out) {
    __shared__ float pl[64];
    int b = blockIdx.x, t = threadIdx.x;
    pl[t] = pooled[b * 64 + t] * (1.0f / 512.0f);
    __syncthreads();
    float a = rb[t];
    for (int cc = 0; cc < 64; ++cc) a += pl[cc] * rw[t * 64 + cc];
    out[b * 64 + t] = a;
}

extern "C" void kernel_launch(void* const* d_in, const int* in_sizes, int n_in,
                              void* d_out, int out_size, void* d_ws, size_t ws_size,
                              hipStream_t stream) {
    const float* emb       = (const float*)d_in[0];
    const float* lin_w     = (const float*)d_in[1];
    const float* att_src   = (const float*)d_in[2];
    const float* att_dst   = (const float*)d_in[3];
    const float* conv_b    = (const float*)d_in[4];
    const float* readout_w = (const float*)d_in[5];
    const float* readout_b = (const float*)d_in[6];
    float* out = (float*)d_out;

    float* ws   = (float*)d_ws;
    float* xbuf = ws;                    // 8 MB
    float* hT   = ws + 2097152;          // 32 MB, channel-pair interleaved (R32)
    float* meta = ws + 10485760;         // 4 MB

    float4* g_rE   = (float4*)meta;                // [256*512] (rank,E1,E2,-)
    float4* g_abk  = (float4*)(meta + 524288);     // [256*512] (aZ,bZ,k,-)
    float*  pooled = ws + 11534336;                // [64*64] over-n sums
    float2* g_sd   = (float2*)(ws + 11538432);     // [256*512] packed (s,d)

    for (int l = 0; l < 3; ++l) {
        const float* xin = (l == 0) ? emb : xbuf;
        lin_kernel<<<1024, 256, 0, stream>>>(xin, lin_w + (size_t)l * 16384,
                                             att_src + l * 256, att_dst + l * 256,
                                             hT, g_sd);
        prep_kernel<<<256, 256, 0, stream>>>(g_sd, g_rE, g_abk);
        attn_agg_fin<<<2048, 256, 0, stream>>>(hT, g_rE, g_abk,
                                               conv_b + l * 64, xbuf, pooled,
                                               (l < 2) ? 1 : 0);
    }
    readout_kernel<<<64, 64, 0, stream>>>(pooled, readout_w, readout_b, out);
}

// Round 18
// 198.275 us; speedup vs baseline: 1.0379x; 1.0379x over previous
//
#include <hip/hip_runtime.h>
#include <math.h>

// Problem constants (fixed by reference): B=64, N=512, D=64, H=4, C=64, L=3
// Workspace layout (floats), ws >= 256 MB:
//   xbuf [0 .. 2097152)          : layer activations x (8 MB)
//   hT   [2097152 .. 10485760)   : h channel-pair interleaved (R32) (32 MB)
//   meta [10485760 .. 11534336)  : g_rE float4 + g_abk float4 (4 MB)
//   pooled [11534336 .. +4096)   : per-(b,c) over-n sums (16 KB)
// History: R23 237 -> R27 236 -> R28 232 -> R29 229 -> R30 201 -> R31 197.5
// -> R32 196.1 BEST. R33 un-fuse lin/prep REGRESSED (205.8): +3 boundaries,
// 4x W re-staging, g_sd round-trip > lin TLP gain. Lesson (consistent since
// R22): boundaries/re-staging cost more than latency depth saves here.
// R34 (this): exact R32 revert + message-reduction (6-for-6 mechanism) on
// prep's last split-pair accesses, all bit-identical:
//   a) sort exchange: {val,id} packed in float2 sVI[1024]; per stage
//      4 stores + 4 loads -> 1 b128 store + 1 b128 load.
//   b) z1suf/z2pre -> interleaved float2 z12[513]: random lookup 2 scalar
//      loads -> 1 float2 load; writes -> one float4 store.
//   c) final sorted writeback as one float2 store.
// absmax must stay exactly 1.907349e-06.
// Decision rule: >=196.1 -> floor is ~196; revert to exact R32 and stop.

using short8  = __attribute__((ext_vector_type(8))) short;
using floatx4 = __attribute__((ext_vector_type(4))) float;

__device__ inline unsigned short f2bf(float f) {
    union { float f; unsigned u; } v; v.f = f;
    unsigned u = v.u + 0x7FFFu + ((v.u >> 16) & 1u);   // round-to-nearest-even
    return (unsigned short)(u >> 16);
}
__device__ inline float bf2f(unsigned short s) {
    union { float f; unsigned u; } v; v.u = ((unsigned)s) << 16;
    return v.f;
}

// 8 floats (two float4) -> split-bf16 hi/lo short8 fragments, in registers.
__device__ inline void cvt8(const float4 a, const float4 b, short8& hi, short8& lo) {
    float f[8] = {a.x, a.y, a.z, a.w, b.x, b.y, b.z, b.w};
    short8 H, L;
#pragma unroll
    for (int i = 0; i < 8; ++i) {
        unsigned short h = f2bf(f[i]);
        H[i] = (short)h;
        L[i] = (short)f2bf(f[i] - bf2f(h));
    }
    hi = H; lo = L;
}

// ---------------------------------------------------------------------------
// Kernel A+B1 fused: linprep v6 (R34) — R32 body + packed prep LDS.
// 512 threads, grid 256, XCD swizzle id%8==b%8, prep on t<256.
// ---------------------------------------------------------------------------
__global__ __launch_bounds__(512) void linprep_kernel(const float* __restrict__ x,
                                                      const float* __restrict__ W,
                                                      const float* __restrict__ att_src,
                                                      const float* __restrict__ att_dst,
                                                      float* __restrict__ hT,
                                                      float4* __restrict__ g_rE,
                                                      float4* __restrict__ g_abk) {
    __shared__ unsigned short WH[64 * 72], WL[64 * 72];
    __shared__ float sA[512], dA[512];      // s/d dots (sA sorted in place)
    __shared__ float2 sVI[1024];            // packed {val,id} exchange buffer
    __shared__ float2 z12[513];             // packed {z1suf, z2pre}
    __shared__ float wred[8];

    const int t  = threadIdx.x;
    // R28 bijective swizzle: id%8 = b%8 (4 head-blocks of b on one XCD).
    const int r8 = blockIdx.x & 7;
    const int q  = blockIdx.x >> 3;       // 0..31
    const int ct = q & 3;                 // head
    const int b  = ((q >> 2) << 3) | r8;  // 0..63
    const int bh = b * 4 + ct;            // meta layout index (unchanged)
    const int c0 = ct * 64;

    // ---- W staging + convert, ONCE per block (512 thr: 2 float4 each) ----
#pragma unroll
    for (int qq = 0; qq < 2; ++qq) {
        int f = qq * 512 + t;
        int wrow = f >> 4, d4 = f & 15;
        float4 v = *(const float4*)(W + (size_t)(c0 + wrow) * 64 + d4 * 4);
        unsigned short h0 = f2bf(v.x), h1 = f2bf(v.y), h2 = f2bf(v.z), h3 = f2bf(v.w);
        ushort4 hi = make_ushort4(h0, h1, h2, h3);
        ushort4 lo = make_ushort4(f2bf(v.x - bf2f(h0)), f2bf(v.y - bf2f(h1)),
                                  f2bf(v.z - bf2f(h2)), f2bf(v.w - bf2f(h3)));
        *(ushort4*)&WH[wrow * 72 + d4 * 4] = hi;
        *(ushort4*)&WL[wrow * 72 + d4 * 4] = lo;
    }
    __syncthreads();

    const int lane = t & 63, wv = t >> 6;   // wv = 0..7
    const int mrow = lane & 15, quad = lane >> 4;

    // ---- per-wave W fragments for ALL 4 channel groups (REGISTERS) ----
    short8 bhf[4][2], blf[4][2];
#pragma unroll
    for (int g = 0; g < 4; ++g)
#pragma unroll
        for (int kk = 0; kk < 2; ++kk) {
            int ko = kk * 32 + quad * 8;
            bhf[g][kk] = *(const short8*)&WH[(g * 16 + mrow) * 72 + ko];
            blf[g][kk] = *(const short8*)&WL[(g * 16 + mrow) * 72 + ko];
        }
    float as_g[4], ad_g[4];
#pragma unroll
    for (int g = 0; g < 4; ++g) {
        as_g[g] = att_src[c0 + g * 16 + mrow];
        ad_g[g] = att_dst[c0 + g * 16 + mrow];
    }

    // ---- lin: wave wv owns tiles wv, wv+8, wv+16, wv+24 (1-deep prefetch) --
    const float* xbase = x + (size_t)(b * 512 + mrow) * 64 + quad * 8;
    float4 nxa = *(const float4*)(xbase + (size_t)wv * 1024);
    float4 nxb = *(const float4*)(xbase + (size_t)wv * 1024 + 4);
    float4 nxc = *(const float4*)(xbase + (size_t)wv * 1024 + 32);
    float4 nxd = *(const float4*)(xbase + (size_t)wv * 1024 + 36);

#pragma unroll 1
    for (int tl = wv; tl < 32; tl += 8) {
        float4 xa = nxa, xb = nxb, xc = nxc, xd = nxd;
        if (tl + 8 < 32) {
            const float* nb = xbase + (size_t)(tl + 8) * 1024;
            nxa = *(const float4*)(nb);
            nxb = *(const float4*)(nb + 4);
            nxc = *(const float4*)(nb + 32);
            nxd = *(const float4*)(nb + 36);
        }
        short8 ah0, al0, ah1, al1;
        cvt8(xa, xb, ah0, al0);
        cvt8(xc, xd, ah1, al1);

        floatx4 acc[4];
#pragma unroll
        for (int g = 0; g < 4; ++g) {
            floatx4 a = {0.f, 0.f, 0.f, 0.f};
            a = __builtin_amdgcn_mfma_f32_16x16x32_bf16(ah0, bhf[g][0], a, 0, 0, 0);
            a = __builtin_amdgcn_mfma_f32_16x16x32_bf16(ah1, bhf[g][1], a, 0, 0, 0);
            a = __builtin_amdgcn_mfma_f32_16x16x32_bf16(ah0, blf[g][0], a, 0, 0, 0);
            a = __builtin_amdgcn_mfma_f32_16x16x32_bf16(ah1, blf[g][1], a, 0, 0, 0);
            a = __builtin_amdgcn_mfma_f32_16x16x32_bf16(al0, bhf[g][0], a, 0, 0, 0);
            a = __builtin_amdgcn_mfma_f32_16x16x32_bf16(al1, bhf[g][1], a, 0, 0, 0);
            acc[g] = a;
        }

        // ---- R32: channel-pair interleaved hT store via lane-pair exchange.
        const int nbase = b * 512 + tl * 16 + quad * 4;
#pragma unroll
        for (int g = 0; g < 4; ++g) {
            float tmp0 = __shfl_xor(acc[g][0], 1, 64);
            float tmp1 = __shfl_xor(acc[g][1], 1, 64);
            float tmp2 = __shfl_xor(acc[g][2], 1, 64);
            float tmp3 = __shfl_xor(acc[g][3], 1, 64);
            const size_t cp = (size_t)(ct * 32 + g * 8 + (mrow >> 1));
            if ((mrow & 1) == 0) {
                *(float4*)&hT[cp * 65536 + (size_t)nbase * 2] =
                    make_float4(acc[g][0], tmp0, acc[g][1], tmp1);
            } else {
                *(float4*)&hT[cp * 65536 + (size_t)(nbase + 2) * 2] =
                    make_float4(tmp2, acc[g][2], tmp3, acc[g][3]);
            }
        }

        float ps[4], pd[4];
#pragma unroll
        for (int reg = 0; reg < 4; ++reg) {
            ps[reg] = acc[0][reg] * as_g[0] + acc[1][reg] * as_g[1]
                    + acc[2][reg] * as_g[2] + acc[3][reg] * as_g[3];
            pd[reg] = acc[0][reg] * ad_g[0] + acc[1][reg] * ad_g[1]
                    + acc[2][reg] * ad_g[2] + acc[3][reg] * ad_g[3];
        }
#pragma unroll
        for (int m = 1; m <= 8; m <<= 1) {
#pragma unroll
            for (int reg = 0; reg < 4; ++reg) {
                ps[reg] += __shfl_xor(ps[reg], m, 64);
                pd[reg] += __shfl_xor(pd[reg], m, 64);
            }
        }
        if (mrow < 4) {
            sA[tl * 16 + quad * 4 + mrow] = ps[mrow];
            dA[tl * 16 + quad * 4 + mrow] = pd[mrow];
        }
    }
    __syncthreads();

    // ======================= prep body: t<256 active ========================
    const bool act = (t < 256);
    const int wid = t >> 6;               // 0..3 when act

    float dreg[2] = {0.f, 0.f};
    if (act) {
        dreg[0] = dA[t];
        dreg[1] = dA[t + 256];
    }

    float v0 = 0.f, v1 = 0.f;
    int id0 = 0, id1 = 0;
    if (act) { v0 = sA[2 * t]; v1 = sA[2 * t + 1]; id0 = 2 * t; id1 = 2 * t + 1; }

    for (int k = 2; k <= 512; k <<= 1) {
        for (int j = k >> 1; j >= 1; j >>= 1) {
            bool asc = ((t & (k >> 1)) == 0);
            if (j == 1) {
                if (act) {
                    bool sw = asc ? (v0 > v1) : (v0 < v1);
                    if (sw) { float tv = v0; v0 = v1; v1 = tv; int ti = id0; id0 = id1; id1 = ti; }
                }
            } else if (j <= 64) {
                if (act) {
                    int m = j >> 1;
                    float w0 = __shfl_xor(v0, m, 64);
                    int  wi0 = __shfl_xor(id0, m, 64);
                    float w1 = __shfl_xor(v1, m, 64);
                    int  wi1 = __shfl_xor(id1, m, 64);
                    bool low = ((t & m) == 0);
                    bool wantmin = (low == asc);
                    if (wantmin ? (w0 < v0) : (w0 > v0)) { v0 = w0; id0 = wi0; }
                    if (wantmin ? (w1 < v1) : (w1 > v1)) { v1 = w1; id1 = wi1; }
                }
            } else {
                int m = j >> 1;
                if (act) {
                    // R34: packed {val,id} exchange — one b128 store.
                    *(float4*)&sVI[2 * t] =
                        make_float4(v0, __int_as_float(id0),
                                    v1, __int_as_float(id1));
                }
                __syncthreads();
                if (act) {
                    int tp = t ^ m;
                    float4 w = *(float4*)&sVI[2 * tp];     // one b128 load
                    float w0 = w.x, w1 = w.z;
                    int  wi0 = __float_as_int(w.y), wi1 = __float_as_int(w.w);
                    bool low = ((t & m) == 0);
                    bool wantmin = (low == asc);
                    if (wantmin ? (w0 < v0) : (w0 > v0)) { v0 = w0; id0 = wi0; }
                    if (wantmin ? (w1 < v1) : (w1 > v1)) { v1 = w1; id1 = wi1; }
                }
                __syncthreads();
            }
        }
    }

    if (act) { *(float2*)&sA[2 * t] = make_float2(v0, v1); }   // one b64 store
    __syncthreads();
    const float M = sA[511];

    float e1_0 = 0.f, e1_1 = 0.f, e2_0 = 0.f, e2_1 = 0.f;
    if (act) {
        e1_0 = __expf(v0 - M);  e1_1 = __expf(v1 - M);
        e2_0 = __expf(0.2f * (v0 - M));  e2_1 = __expf(0.2f * (v1 - M));
        const int base = bh * 512;
        g_rE[base + id0] = make_float4(__int_as_float(2 * t),     e1_0, e2_0, 0.f);
        g_rE[base + id1] = make_float4(__int_as_float(2 * t + 1), e1_1, e2_1, 0.f);
    }

    float S1 = e1_0 + e1_1, S2 = e2_0 + e2_1;
    float i1 = S1, i2 = S2;
    if (act) {
        for (int off = 1; off < 64; off <<= 1) {
            float u1 = __shfl_up(i1, off, 64);
            float u2 = __shfl_up(i2, off, 64);
            if (lane >= off) { i1 += u1; i2 += u2; }
        }
        if (lane == 63) { wred[wid] = i1; wred[4 + wid] = i2; }
    }
    __syncthreads();
    if (act) {
        float off1 = 0.f, off2 = 0.f;
        for (int w = 0; w < wid; ++w) { off1 += wred[w]; off2 += wred[4 + w]; }
        const float T1 = wred[0] + wred[1] + wred[2] + wred[3];
        const float T2 = wred[4] + wred[5] + wred[6] + wred[7];
        float pre1 = off1 + i1 - S1;
        float pre2 = off2 + i2 - S2;
        // R34: packed z-table — one float4 store covers z12[2t..2t+1].
        *(float4*)&z12[2 * t] = make_float4(T1 - pre1,        pre2,
                                            T1 - pre1 - e1_0, pre2 + e2_0);
        if (t == 0) z12[512] = make_float2(0.f, T2);
    }
    __syncthreads();

    if (act) {
        for (int rr = 0; rr < 2; ++rr) {
            int i = t + rr * 256;
            float d = dreg[rr];
            int lo = 0, hi = 512;
            while (lo < hi) {
                int mid = (lo + hi) >> 1;
                if (d + sA[mid] >= 0.f) hi = mid; else lo = mid + 1;
            }
            int k = lo;
            float g = d + M;
            float G = (g >= 0.f) ? g : 0.2f * g;
            float al = __expf(g - G);
            float be = __expf(0.2f * g - G);
            float2 z = z12[k];                        // one float2 load
            float Z = al * z.x + be * z.y;
            float inv = 1.0f / Z;
            g_abk[bh * 512 + i] = make_float4(al * inv, be * inv,
                                              __int_as_float(k), 0.f);
        }
    }
}

// ---------------------------------------------------------------------------
// Kernel B2: attn_agg_fin v11 (R32, UNCHANGED) — float4 LDS tables + float2
// hT reads + fused pooling + optional x store. grid 2048, 256 thr.
// ---------------------------------------------------------------------------
__global__ __launch_bounds__(256) void attn_agg_fin(const float* __restrict__ hT,
                                                    const float4* __restrict__ g_rE,
                                                    const float4* __restrict__ g_abk,
                                                    const float* __restrict__ bias,
                                                    float* __restrict__ x,
                                                    float* __restrict__ pooled,
                                                    int storex) {
    // R27 bijective swizzle: id%8 = b%8.
    const int r8 = blockIdx.x & 7;
    const int qq = blockIdx.x >> 3;
    const int cg = qq & 31;                // 0..31
    const int b  = ((qq >> 5) << 3) | r8;  // 0..63
    const int c0 = cg * 2;
    const int t = threadIdx.x;
    const int lane = t & 63, wv = t >> 6;  // wv = head 0..3

    __shared__ float4 A12[4][512];         // {A1c0, A2c0, A1c1, A2c1}
    __shared__ float tots[4][2];
    __shared__ float sredP[4][2];

    {
        const int bh = b * 4 + wv;
        const int base = bh * 512;
        const float* hTb = hT + (size_t)(wv * 32 + cg) * 65536 + (size_t)(b * 512) * 2;
#pragma unroll
        for (int it = 0; it < 8; ++it) {
            int j = it * 64 + lane;
            float4 rE = g_rE[base + j];          // packed (rank, E1, E2)
            int rk = __float_as_int(rE.x);
            float2 hv = *(const float2*)&hTb[j * 2];
            int pk = ((rk & 7) << 6) | (rk >> 3);
            A12[wv][pk] = make_float4(rE.y * hv.x, rE.z * hv.x,
                                      rE.y * hv.y, rE.z * hv.y);   // one b128
        }
        float a1c0[8], a2c0[8], a1c1[8], a2c1[8];
#pragma unroll
        for (int i = 0; i < 8; ++i) {
            float4 vv = A12[wv][i * 64 + lane];
            a1c0[i] = vv.x; a2c0[i] = vv.y; a1c1[i] = vv.z; a2c1[i] = vv.w;
        }
        float s10 = 0.f, s20 = 0.f, s11 = 0.f, s21 = 0.f;
#pragma unroll
        for (int i = 0; i < 8; ++i) {
            s10 += a1c0[i]; s20 += a2c0[i]; s11 += a1c1[i]; s21 += a2c1[i];
        }
        float suf0 = s10, suf1 = s11;
#pragma unroll
        for (int off = 1; off < 64; off <<= 1) {
            float u0 = __shfl_down(suf0, off, 64);
            float u1 = __shfl_down(suf1, off, 64);
            if (lane + off < 64) { suf0 += u0; suf1 += u1; }
        }
        float run0 = suf0 - s10, run1 = suf1 - s11;      // exclusive suffix
        float pre0 = s20, pre1 = s21;
#pragma unroll
        for (int off = 1; off < 64; off <<= 1) {
            float u0 = __shfl_up(pre0, off, 64);
            float u1 = __shfl_up(pre1, off, 64);
            if (lane >= off) { pre0 += u0; pre1 += u1; }
        }
        float run20 = pre0 - s20, run21 = pre1 - s21;    // exclusive prefix
        if (lane == 63) { tots[wv][0] = pre0; tots[wv][1] = pre1; }
#pragma unroll
        for (int i = 7; i >= 0; --i) {
            run0 += a1c0[i]; a1c0[i] = run0;             // incl suffix
            run1 += a1c1[i]; a1c1[i] = run1;
        }
#pragma unroll
        for (int i = 0; i < 8; ++i) {
            float tv0 = a2c0[i]; a2c0[i] = run20; run20 += tv0;  // excl prefix
            float tv1 = a2c1[i]; a2c1[i] = run21; run21 += tv1;
        }
#pragma unroll
        for (int i = 0; i < 8; ++i)
            A12[wv][i * 64 + lane] = make_float4(a1c0[i], a2c0[i],
                                                 a1c1[i], a2c1[i]);  // one b128
    }
    __syncthreads();

    const float bv0 = bias[c0], bv1 = bias[c0 + 1];
    float p0 = 0.f, p1 = 0.f;              // per-thread pooled partials
#pragma unroll
    for (int rr = 0; rr < 2; ++rr) {
        const int i = t + rr * 256;
        float a0 = 0.f, a1 = 0.f;
#pragma unroll
        for (int head = 0; head < 4; ++head) {
            const int base = (b * 4 + head) * 512;
            float4 abk = g_abk[base + i];        // packed (aZ, bZ, k)
            int k = __float_as_int(abk.z);
            if (k < 512) {
                int pk = ((k & 7) << 6) | (k >> 3);
                float4 vv = A12[head][pk];       // one random b128
                a0 += abk.x * vv.x + abk.y * vv.y;
                a1 += abk.x * vv.z + abk.y * vv.w;
            } else {
                a0 += abk.y * tots[head][0];
                a1 += abk.y * tots[head][1];
            }
        }
        float2 o = make_float2(fmaxf(0.25f * a0 + bv0, 0.f),
                               fmaxf(0.25f * a1 + bv1, 0.f));
        if (storex) *(float2*)&x[(size_t)(b * 512 + i) * 64 + c0] = o;
        p0 += o.x; p1 += o.y;
    }

    // Fused pooling: this block exclusively owns (b, c0..c0+1) over all n.
#pragma unroll
    for (int m = 1; m <= 32; m <<= 1) {
        p0 += __shfl_xor(p0, m, 64);
        p1 += __shfl_xor(p1, m, 64);
    }
    if (lane == 0) { sredP[wv][0] = p0; sredP[wv][1] = p1; }
    __syncthreads();
    if (t == 0) {
        pooled[b * 64 + c0]     = sredP[0][0] + sredP[1][0] + sredP[2][0] + sredP[3][0];
        pooled[b * 64 + c0 + 1] = sredP[0][1] + sredP[1][1] + sredP[2][1] + sredP[3][1];
    }
}

// ---------------------------------------------------------------------------
// Kernel D: readout v2 — consumes 16KB pooled sums. grid 64 x 64 threads.
// ---------------------------------------------------------------------------
__global__ __launch_bounds__(64) void readout_kernel(const float* __restrict__ pooled,
                                                     const float* __restrict__ rw,
                                                     const float* __restrict__ rb,
                                                     float* __restrict__ out) {
    __shared__ float pl[64];
    int b = blockIdx.x, t = threadIdx.x;
    pl[t] = pooled[b * 64 + t] * (1.0f / 512.0f);
    __syncthreads();
    float a = rb[t];
    for (int cc = 0; cc < 64; ++cc) a += pl[cc] * rw[t * 64 + cc];
    out[b * 64 + t] = a;
}

extern "C" void kernel_launch(void* const* d_in, const int* in_sizes, int n_in,
                              void* d_out, int out_size, void* d_ws, size_t ws_size,
                              hipStream_t stream) {
    const float* emb       = (const float*)d_in[0];
    const float* lin_w     = (const float*)d_in[1];
    const float* att_src   = (const float*)d_in[2];
    const float* att_dst   = (const float*)d_in[3];
    const float* conv_b    = (const float*)d_in[4];
    const float* readout_w = (const float*)d_in[5];
    const float* readout_b = (const float*)d_in[6];
    float* out = (float*)d_out;

    float* ws   = (float*)d_ws;
    float* xbuf = ws;                    // 8 MB
    float* hT   = ws + 2097152;          // 32 MB, channel-pair interleaved (R32)
    float* meta = ws + 10485760;         // 4 MB

    float4* g_rE   = (float4*)meta;                // [256*512] (rank,E1,E2,-)
    float4* g_abk  = (float4*)(meta + 524288);     // [256*512] (aZ,bZ,k,-)
    float*  pooled = ws + 11534336;                // [64*64] over-n sums

    for (int l = 0; l < 3; ++l) {
        const float* xin = (l == 0) ? emb : xbuf;
        linprep_kernel<<<256, 512, 0, stream>>>(xin, lin_w + (size_t)l * 16384,
                                                att_src + l * 256, att_dst + l * 256,
                                                hT, g_rE, g_abk);
        attn_agg_fin<<<2048, 256, 0, stream>>>(hT, g_rE, g_abk,
                                               conv_b + l * 64, xbuf, pooled,
                                               (l < 2) ? 1 : 0);
    }
    readout_kernel<<<64, 64, 0, stream>>>(pooled, readout_w, readout_b, out);
}

// Round 19
// 196.774 us; speedup vs baseline: 1.0458x; 1.0076x over previous
//
#include <hip/hip_runtime.h>
#include <math.h>

// Problem constants (fixed by reference): B=64, N=512, D=64, H=4, C=64, L=3
// Workspace layout (floats), ws >= 256 MB:
//   xbuf [0 .. 2097152)          : layer activations x (8 MB)
//   hT   [2097152 .. 10485760)   : h channel-pair interleaved (R32):
//                                  [head*32+cp][(b*512+n)*2 + parity] (32 MB)
//   meta [10485760 .. 11534336)  : g_rE float4 + g_abk float4 (4 MB)
//   pooled [11534336 .. +4096)   : per-(b,c) over-n sums (16 KB)
// FINAL STATE: exact R32 (196.1 us, best measured). Session trajectory:
// 265.6 -> R23 237.2 (wave-indep fused linprep) -> R27 235.9 (agg XCD
// swizzle) -> R28 231.6 (linprep XCD swizzle + meta float2 packing) ->
// R29 229.2 (512-thr linprep + float4 packing) -> R30 201.4 (A12 float2
// LDS interleave + fused pooling) -> R31 197.5 (float4 LDS tables + storex
// skip) -> R32 196.1 (channel-pair hT stream).
// Refuted arcs: mega-kernel grid barriers (R17-19: ~45us/barrier floor),
// b-local full fusion (R24), redundant-sort occupancy (R26), lin/prep
// un-fuse (R33), prep LDS packing (R34: sort not on critical path).
// Remaining budget: ~43us harness fill AT HBM ROOFLINE (83% peak) + two
// latency-bound kernels with every measured lever exhausted + ~10us of
// dispatch boundaries whose only remover costs 45us/barrier.

using short8  = __attribute__((ext_vector_type(8))) short;
using floatx4 = __attribute__((ext_vector_type(4))) float;

__device__ inline unsigned short f2bf(float f) {
    union { float f; unsigned u; } v; v.f = f;
    unsigned u = v.u + 0x7FFFu + ((v.u >> 16) & 1u);   // round-to-nearest-even
    return (unsigned short)(u >> 16);
}
__device__ inline float bf2f(unsigned short s) {
    union { float f; unsigned u; } v; v.u = ((unsigned)s) << 16;
    return v.f;
}

// 8 floats (two float4) -> split-bf16 hi/lo short8 fragments, in registers.
__device__ inline void cvt8(const float4 a, const float4 b, short8& hi, short8& lo) {
    float f[8] = {a.x, a.y, a.z, a.w, b.x, b.y, b.z, b.w};
    short8 H, L;
#pragma unroll
    for (int i = 0; i < 8; ++i) {
        unsigned short h = f2bf(f[i]);
        H[i] = (short)h;
        L[i] = (short)f2bf(f[i] - bf2f(h));
    }
    hi = H; lo = L;
}

// ---------------------------------------------------------------------------
// Kernel A+B1 fused: linprep v5 (R32) — R29 body + channel-pair hT stores.
// 512 threads, grid 256, XCD swizzle id%8==b%8, prep on t<256.
// ---------------------------------------------------------------------------
__global__ __launch_bounds__(512) void linprep_kernel(const float* __restrict__ x,
                                                      const float* __restrict__ W,
                                                      const float* __restrict__ att_src,
                                                      const float* __restrict__ att_dst,
                                                      float* __restrict__ hT,
                                                      float4* __restrict__ g_rE,
                                                      float4* __restrict__ g_abk) {
    __shared__ unsigned short WH[64 * 72], WL[64 * 72];
    __shared__ float sA[512], dA[512];      // s/d dots (then sA sorted in place)
    __shared__ int   s_idxE[512];
    __shared__ float z1suf[513], z2pre[513];
    __shared__ float wred[8];

    const int t  = threadIdx.x;
    // R28 bijective swizzle: id%8 = b%8 (4 head-blocks of b on one XCD).
    const int r8 = blockIdx.x & 7;
    const int q  = blockIdx.x >> 3;       // 0..31
    const int ct = q & 3;                 // head
    const int b  = ((q >> 2) << 3) | r8;  // 0..63
    const int bh = b * 4 + ct;            // meta layout index (unchanged)
    const int c0 = ct * 64;

    // ---- W staging + convert, ONCE per block (512 thr: 2 float4 each) ----
#pragma unroll
    for (int qq = 0; qq < 2; ++qq) {
        int f = qq * 512 + t;
        int wrow = f >> 4, d4 = f & 15;
        float4 v = *(const float4*)(W + (size_t)(c0 + wrow) * 64 + d4 * 4);
        unsigned short h0 = f2bf(v.x), h1 = f2bf(v.y), h2 = f2bf(v.z), h3 = f2bf(v.w);
        ushort4 hi = make_ushort4(h0, h1, h2, h3);
        ushort4 lo = make_ushort4(f2bf(v.x - bf2f(h0)), f2bf(v.y - bf2f(h1)),
                                  f2bf(v.z - bf2f(h2)), f2bf(v.w - bf2f(h3)));
        *(ushort4*)&WH[wrow * 72 + d4 * 4] = hi;
        *(ushort4*)&WL[wrow * 72 + d4 * 4] = lo;
    }
    __syncthreads();

    const int lane = t & 63, wv = t >> 6;   // wv = 0..7
    const int mrow = lane & 15, quad = lane >> 4;

    // ---- per-wave W fragments for ALL 4 channel groups (REGISTERS) ----
    short8 bhf[4][2], blf[4][2];
#pragma unroll
    for (int g = 0; g < 4; ++g)
#pragma unroll
        for (int kk = 0; kk < 2; ++kk) {
            int ko = kk * 32 + quad * 8;
            bhf[g][kk] = *(const short8*)&WH[(g * 16 + mrow) * 72 + ko];
            blf[g][kk] = *(const short8*)&WL[(g * 16 + mrow) * 72 + ko];
        }
    float as_g[4], ad_g[4];
#pragma unroll
    for (int g = 0; g < 4; ++g) {
        as_g[g] = att_src[c0 + g * 16 + mrow];
        ad_g[g] = att_dst[c0 + g * 16 + mrow];
    }

    // ---- lin: wave wv owns tiles wv, wv+8, wv+16, wv+24 (1-deep prefetch) --
    const float* xbase = x + (size_t)(b * 512 + mrow) * 64 + quad * 8;
    float4 nxa = *(const float4*)(xbase + (size_t)wv * 1024);
    float4 nxb = *(const float4*)(xbase + (size_t)wv * 1024 + 4);
    float4 nxc = *(const float4*)(xbase + (size_t)wv * 1024 + 32);
    float4 nxd = *(const float4*)(xbase + (size_t)wv * 1024 + 36);

#pragma unroll 1
    for (int tl = wv; tl < 32; tl += 8) {
        float4 xa = nxa, xb = nxb, xc = nxc, xd = nxd;
        if (tl + 8 < 32) {
            const float* nb = xbase + (size_t)(tl + 8) * 1024;
            nxa = *(const float4*)(nb);
            nxb = *(const float4*)(nb + 4);
            nxc = *(const float4*)(nb + 32);
            nxd = *(const float4*)(nb + 36);
        }
        short8 ah0, al0, ah1, al1;
        cvt8(xa, xb, ah0, al0);
        cvt8(xc, xd, ah1, al1);

        floatx4 acc[4];
#pragma unroll
        for (int g = 0; g < 4; ++g) {
            floatx4 a = {0.f, 0.f, 0.f, 0.f};
            a = __builtin_amdgcn_mfma_f32_16x16x32_bf16(ah0, bhf[g][0], a, 0, 0, 0);
            a = __builtin_amdgcn_mfma_f32_16x16x32_bf16(ah1, bhf[g][1], a, 0, 0, 0);
            a = __builtin_amdgcn_mfma_f32_16x16x32_bf16(ah0, blf[g][0], a, 0, 0, 0);
            a = __builtin_amdgcn_mfma_f32_16x16x32_bf16(ah1, blf[g][1], a, 0, 0, 0);
            a = __builtin_amdgcn_mfma_f32_16x16x32_bf16(al0, bhf[g][0], a, 0, 0, 0);
            a = __builtin_amdgcn_mfma_f32_16x16x32_bf16(al1, bhf[g][1], a, 0, 0, 0);
            acc[g] = a;
        }

        // ---- R32: channel-pair interleaved hT store via lane-pair exchange.
        // hT2[(ct*32 + g*8 + mrow>>1)*65536 + (b*512 + n)*2 + (mrow&1)]
        // even lane stores n0..n1 {e0,o0,e1,o1}; odd lane n2..n3 {e2,o2,e3,o3}.
        const int nbase = b * 512 + tl * 16 + quad * 4;
#pragma unroll
        for (int g = 0; g < 4; ++g) {
            float tmp0 = __shfl_xor(acc[g][0], 1, 64);
            float tmp1 = __shfl_xor(acc[g][1], 1, 64);
            float tmp2 = __shfl_xor(acc[g][2], 1, 64);
            float tmp3 = __shfl_xor(acc[g][3], 1, 64);
            const size_t cp = (size_t)(ct * 32 + g * 8 + (mrow >> 1));
            if ((mrow & 1) == 0) {
                *(float4*)&hT[cp * 65536 + (size_t)nbase * 2] =
                    make_float4(acc[g][0], tmp0, acc[g][1], tmp1);
            } else {
                *(float4*)&hT[cp * 65536 + (size_t)(nbase + 2) * 2] =
                    make_float4(tmp2, acc[g][2], tmp3, acc[g][3]);
            }
        }

        float ps[4], pd[4];
#pragma unroll
        for (int reg = 0; reg < 4; ++reg) {
            ps[reg] = acc[0][reg] * as_g[0] + acc[1][reg] * as_g[1]
                    + acc[2][reg] * as_g[2] + acc[3][reg] * as_g[3];
            pd[reg] = acc[0][reg] * ad_g[0] + acc[1][reg] * ad_g[1]
                    + acc[2][reg] * ad_g[2] + acc[3][reg] * ad_g[3];
        }
#pragma unroll
        for (int m = 1; m <= 8; m <<= 1) {
#pragma unroll
            for (int reg = 0; reg < 4; ++reg) {
                ps[reg] += __shfl_xor(ps[reg], m, 64);
                pd[reg] += __shfl_xor(pd[reg], m, 64);
            }
        }
        if (mrow < 4) {
            sA[tl * 16 + quad * 4 + mrow] = ps[mrow];
            dA[tl * 16 + quad * 4 + mrow] = pd[mrow];
        }
    }
    __syncthreads();

    // ======================= prep body: t<256 active ========================
    const bool act = (t < 256);
    const int wid = t >> 6;               // 0..3 when act

    float dreg[2] = {0.f, 0.f};
    if (act) {
        dreg[0] = dA[t];
        dreg[1] = dA[t + 256];
    }

    float v0 = 0.f, v1 = 0.f;
    int id0 = 0, id1 = 0;
    if (act) { v0 = sA[2 * t]; v1 = sA[2 * t + 1]; id0 = 2 * t; id1 = 2 * t + 1; }

    for (int k = 2; k <= 512; k <<= 1) {
        for (int j = k >> 1; j >= 1; j >>= 1) {
            bool asc = ((t & (k >> 1)) == 0);
            if (j == 1) {
                if (act) {
                    bool sw = asc ? (v0 > v1) : (v0 < v1);
                    if (sw) { float tv = v0; v0 = v1; v1 = tv; int ti = id0; id0 = id1; id1 = ti; }
                }
            } else if (j <= 64) {
                if (act) {
                    int m = j >> 1;
                    float w0 = __shfl_xor(v0, m, 64);
                    int  wi0 = __shfl_xor(id0, m, 64);
                    float w1 = __shfl_xor(v1, m, 64);
                    int  wi1 = __shfl_xor(id1, m, 64);
                    bool low = ((t & m) == 0);
                    bool wantmin = (low == asc);
                    if (wantmin ? (w0 < v0) : (w0 > v0)) { v0 = w0; id0 = wi0; }
                    if (wantmin ? (w1 < v1) : (w1 > v1)) { v1 = w1; id1 = wi1; }
                }
            } else {
                int m = j >> 1;
                if (act) {
                    sA[2 * t] = v0; sA[2 * t + 1] = v1;
                    s_idxE[2 * t] = id0; s_idxE[2 * t + 1] = id1;
                }
                __syncthreads();
                if (act) {
                    int tp = t ^ m;
                    float w0 = sA[2 * tp], w1 = sA[2 * tp + 1];
                    int wi0 = s_idxE[2 * tp], wi1 = s_idxE[2 * tp + 1];
                    bool low = ((t & m) == 0);
                    bool wantmin = (low == asc);
                    if (wantmin ? (w0 < v0) : (w0 > v0)) { v0 = w0; id0 = wi0; }
                    if (wantmin ? (w1 < v1) : (w1 > v1)) { v1 = w1; id1 = wi1; }
                }
                __syncthreads();
            }
        }
    }

    if (act) { sA[2 * t] = v0; sA[2 * t + 1] = v1; }
    __syncthreads();
    const float M = sA[511];

    float e1_0 = 0.f, e1_1 = 0.f, e2_0 = 0.f, e2_1 = 0.f;
    if (act) {
        e1_0 = __expf(v0 - M);  e1_1 = __expf(v1 - M);
        e2_0 = __expf(0.2f * (v0 - M));  e2_1 = __expf(0.2f * (v1 - M));
        const int base = bh * 512;
        g_rE[base + id0] = make_float4(__int_as_float(2 * t),     e1_0, e2_0, 0.f);
        g_rE[base + id1] = make_float4(__int_as_float(2 * t + 1), e1_1, e2_1, 0.f);
    }

    float S1 = e1_0 + e1_1, S2 = e2_0 + e2_1;
    float i1 = S1, i2 = S2;
    if (act) {
        for (int off = 1; off < 64; off <<= 1) {
            float u1 = __shfl_up(i1, off, 64);
            float u2 = __shfl_up(i2, off, 64);
            if (lane >= off) { i1 += u1; i2 += u2; }
        }
        if (lane == 63) { wred[wid] = i1; wred[4 + wid] = i2; }
    }
    __syncthreads();
    if (act) {
        float off1 = 0.f, off2 = 0.f;
        for (int w = 0; w < wid; ++w) { off1 += wred[w]; off2 += wred[4 + w]; }
        const float T1 = wred[0] + wred[1] + wred[2] + wred[3];
        const float T2 = wred[4] + wred[5] + wred[6] + wred[7];
        float pre1 = off1 + i1 - S1;
        float pre2 = off2 + i2 - S2;
        z1suf[2 * t] = T1 - pre1;
        z1suf[2 * t + 1] = T1 - pre1 - e1_0;
        z2pre[2 * t] = pre2;
        z2pre[2 * t + 1] = pre2 + e2_0;
        if (t == 0) { z1suf[512] = 0.f; z2pre[512] = T2; }
    }
    __syncthreads();

    if (act) {
        for (int rr = 0; rr < 2; ++rr) {
            int i = t + rr * 256;
            float d = dreg[rr];
            int lo = 0, hi = 512;
            while (lo < hi) {
                int mid = (lo + hi) >> 1;
                if (d + sA[mid] >= 0.f) hi = mid; else lo = mid + 1;
            }
            int k = lo;
            float g = d + M;
            float G = (g >= 0.f) ? g : 0.2f * g;
            float al = __expf(g - G);
            float be = __expf(0.2f * g - G);
            float Z = al * z1suf[k] + be * z2pre[k];
            float inv = 1.0f / Z;
            g_abk[bh * 512 + i] = make_float4(al * inv, be * inv,
                                              __int_as_float(k), 0.f);
        }
    }
}

// ---------------------------------------------------------------------------
// Kernel B2: attn_agg_fin v11 (R32) — float4 LDS tables + float2 hT reads
// (channel-pair interleaved) + fused pooling + optional x store.
// grid = 2048 blocks, 256 thr (4 waves = 4 heads).
// ---------------------------------------------------------------------------
__global__ __launch_bounds__(256) void attn_agg_fin(const float* __restrict__ hT,
                                                    const float4* __restrict__ g_rE,
                                                    const float4* __restrict__ g_abk,
                                                    const float* __restrict__ bias,
                                                    float* __restrict__ x,
                                                    float* __restrict__ pooled,
                                                    int storex) {
    // R27 bijective swizzle: id%8 = b%8.
    const int r8 = blockIdx.x & 7;
    const int qq = blockIdx.x >> 3;
    const int cg = qq & 31;                // 0..31
    const int b  = ((qq >> 5) << 3) | r8;  // 0..63
    const int c0 = cg * 2;
    const int t = threadIdx.x;
    const int lane = t & 63, wv = t >> 6;  // wv = head 0..3

    __shared__ float4 A12[4][512];         // {A1c0, A2c0, A1c1, A2c1}
    __shared__ float tots[4][2];
    __shared__ float sredP[4][2];

    {
        const int bh = b * 4 + wv;
        const int base = bh * 512;
        // R32: channel-pair stream — one float2 per node j.
        const float* hTb = hT + (size_t)(wv * 32 + cg) * 65536 + (size_t)(b * 512) * 2;
#pragma unroll
        for (int it = 0; it < 8; ++it) {
            int j = it * 64 + lane;
            float4 rE = g_rE[base + j];          // packed (rank, E1, E2)
            int rk = __float_as_int(rE.x);
            float2 hv = *(const float2*)&hTb[j * 2];   // {h[c0][j], h[c0+1][j]}
            int pk = ((rk & 7) << 6) | (rk >> 3);
            A12[wv][pk] = make_float4(rE.y * hv.x, rE.z * hv.x,
                                      rE.y * hv.y, rE.z * hv.y);   // one b128
        }
        // scan: all four planes in one pass (per-plane op order = R30)
        float a1c0[8], a2c0[8], a1c1[8], a2c1[8];
#pragma unroll
        for (int i = 0; i < 8; ++i) {
            float4 vv = A12[wv][i * 64 + lane];                // one b128
            a1c0[i] = vv.x; a2c0[i] = vv.y; a1c1[i] = vv.z; a2c1[i] = vv.w;
        }
        float s10 = 0.f, s20 = 0.f, s11 = 0.f, s21 = 0.f;
#pragma unroll
        for (int i = 0; i < 8; ++i) {
            s10 += a1c0[i]; s20 += a2c0[i]; s11 += a1c1[i]; s21 += a2c1[i];
        }
        float suf0 = s10, suf1 = s11;
#pragma unroll
        for (int off = 1; off < 64; off <<= 1) {
            float u0 = __shfl_down(suf0, off, 64);
            float u1 = __shfl_down(suf1, off, 64);
            if (lane + off < 64) { suf0 += u0; suf1 += u1; }
        }
        float run0 = suf0 - s10, run1 = suf1 - s11;      // exclusive suffix
        float pre0 = s20, pre1 = s21;
#pragma unroll
        for (int off = 1; off < 64; off <<= 1) {
            float u0 = __shfl_up(pre0, off, 64);
            float u1 = __shfl_up(pre1, off, 64);
            if (lane >= off) { pre0 += u0; pre1 += u1; }
        }
        float run20 = pre0 - s20, run21 = pre1 - s21;    // exclusive prefix
        if (lane == 63) { tots[wv][0] = pre0; tots[wv][1] = pre1; }
#pragma unroll
        for (int i = 7; i >= 0; --i) {
            run0 += a1c0[i]; a1c0[i] = run0;             // incl suffix
            run1 += a1c1[i]; a1c1[i] = run1;
        }
#pragma unroll
        for (int i = 0; i < 8; ++i) {
            float tv0 = a2c0[i]; a2c0[i] = run20; run20 += tv0;  // excl prefix
            float tv1 = a2c1[i]; a2c1[i] = run21; run21 += tv1;
        }
#pragma unroll
        for (int i = 0; i < 8; ++i)
            A12[wv][i * 64 + lane] = make_float4(a1c0[i], a2c0[i],
                                                 a1c1[i], a2c1[i]);  // one b128
    }
    __syncthreads();

    const float bv0 = bias[c0], bv1 = bias[c0 + 1];
    float p0 = 0.f, p1 = 0.f;              // per-thread pooled partials
#pragma unroll
    for (int rr = 0; rr < 2; ++rr) {
        const int i = t + rr * 256;
        float a0 = 0.f, a1 = 0.f;
#pragma unroll
        for (int head = 0; head < 4; ++head) {
            const int base = (b * 4 + head) * 512;
            float4 abk = g_abk[base + i];        // packed (aZ, bZ, k)
            int k = __float_as_int(abk.z);
            if (k < 512) {
                int pk = ((k & 7) << 6) | (k >> 3);
                float4 vv = A12[head][pk];       // one random b128
                a0 += abk.x * vv.x + abk.y * vv.y;
                a1 += abk.x * vv.z + abk.y * vv.w;
            } else {
                a0 += abk.y * tots[head][0];
                a1 += abk.y * tots[head][1];
            }
        }
        float2 o = make_float2(fmaxf(0.25f * a0 + bv0, 0.f),
                               fmaxf(0.25f * a1 + bv1, 0.f));
        if (storex) *(float2*)&x[(size_t)(b * 512 + i) * 64 + c0] = o;
        p0 += o.x; p1 += o.y;
    }

    // Fused pooling: this block exclusively owns (b, c0..c0+1) over all n.
#pragma unroll
    for (int m = 1; m <= 32; m <<= 1) {
        p0 += __shfl_xor(p0, m, 64);
        p1 += __shfl_xor(p1, m, 64);
    }
    if (lane == 0) { sredP[wv][0] = p0; sredP[wv][1] = p1; }
    __syncthreads();
    if (t == 0) {
        pooled[b * 64 + c0]     = sredP[0][0] + sredP[1][0] + sredP[2][0] + sredP[3][0];
        pooled[b * 64 + c0 + 1] = sredP[0][1] + sredP[1][1] + sredP[2][1] + sredP[3][1];
    }
}

// ---------------------------------------------------------------------------
// Kernel D: readout v2 — consumes 16KB pooled sums. grid 64 x 64 threads.
// ---------------------------------------------------------------------------
__global__ __launch_bounds__(64) void readout_kernel(const float* __restrict__ pooled,
                                                     const float* __restrict__ rw,
                                                     const float* __restrict__ rb,
                                                     float* __restrict__ out) {
    __shared__ float pl[64];
    int b = blockIdx.x, t = threadIdx.x;
    pl[t] = pooled[b * 64 + t] * (1.0f / 512.0f);
    __syncthreads();
    float a = rb[t];
    for (int cc = 0; cc < 64; ++cc) a += pl[cc] * rw[t * 64 + cc];
    out[b * 64 + t] = a;
}

extern "C" void kernel_launch(void* const* d_in, const int* in_sizes, int n_in,
                              void* d_out, int out_size, void* d_ws, size_t ws_size,
                              hipStream_t stream) {
    const float* emb       = (const float*)d_in[0];
    const float* lin_w     = (const float*)d_in[1];
    const float* att_src   = (const float*)d_in[2];
    const float* att_dst   = (const float*)d_in[3];
    const float* conv_b    = (const float*)d_in[4];
    const float* readout_w = (const float*)d_in[5];
    const float* readout_b = (const float*)d_in[6];
    float* out = (float*)d_out;

    float* ws   = (float*)d_ws;
    float* xbuf = ws;                    // 8 MB
    float* hT   = ws + 2097152;          // 32 MB, channel-pair interleaved (R32)
    float* meta = ws + 10485760;         // 4 MB

    float4* g_rE   = (float4*)meta;                // [256*512] (rank,E1,E2,-)
    float4* g_abk  = (float4*)(meta + 524288);     // [256*512] (aZ,bZ,k,-)
    float*  pooled = ws + 11534336;                // [64*64] over-n sums

    for (int l = 0; l < 3; ++l) {
        const float* xin = (l == 0) ? emb : xbuf;
        linprep_kernel<<<256, 512, 0, stream>>>(xin, lin_w + (size_t)l * 16384,
                                                att_src + l * 256, att_dst + l * 256,
                                                hT, g_rE, g_abk);
        attn_agg_fin<<<2048, 256, 0, stream>>>(hT, g_rE, g_abk,
                                               conv_b + l * 64, xbuf, pooled,
                                               (l < 2) ? 1 : 0);
    }
    readout_kernel<<<64, 64, 0, stream>>>(pooled, readout_w, readout_b, out);
}